// Round 12
// baseline (584.214 us; speedup 1.0000x reference)
//
#include <hip/hip_runtime.h>

typedef __bf16 bf16;
typedef __bf16 bf16x8 __attribute__((ext_vector_type(8)));
typedef __bf16 bf16x4 __attribute__((ext_vector_type(4)));
typedef __bf16 bf16x2 __attribute__((ext_vector_type(2)));
typedef float f32x4 __attribute__((ext_vector_type(4)));

#define MFMA16(a,b,c) __builtin_amdgcn_mfma_f32_16x16x32_bf16((a),(b),(c),0,0,0)

#define NPTS 4096
#define CIN 512
#define DIM 128
#define PH 64
#define HID 512

// ws layout (bytes)
#define OFF_WQS 0u                  // bf16 [128][512] folded w_q@w_sq
#define OFF_WKO (128u*1024u)        // bf16 [128][512] folded w_k@w_so
#define OFF_WVO (256u*1024u)        // bf16 [128][512] folded w_v@w_so
#define OFF_BQS (384u*1024u)        // f32 [128]
#define OFF_BKO (385u*1024u)
#define OFF_BVO (386u*1024u)
#define OFF_S1  (387u*1024u)        // f32 [64]
#define OFF_T1  (388u*1024u)
#define OFF_S2  (389u*1024u)        // f32 [512]
#define OFF_T2  (391u*1024u)        // f32 [512]
#define OFF_CW  (400u*1024u)        // bf16 [wp2 8192 | wa1 65536 | wa2 65536 | we 65536]
#define OFF_QT  (1u<<20)            // bf16 [B][4096][128]
#define OFF_KT  (OFF_QT + (4u<<20))
#define OFF_VT  (OFF_QT + (8u<<20))
#define OFF_IDX (OFF_QT + (12u<<20))
#define WS_NEED (OFF_QT + (13u<<20))

struct P {
  const float* in[31];
  char* ws;
  float* out;
  int ybase;
};

template<int C> __device__ __forceinline__ float rorf(float x){
  return __int_as_float(__builtin_amdgcn_mov_dpp(__float_as_int(x), 0x120|C, 0xF, 0xF, true));
}
__device__ __forceinline__ float red16max(float x){
  x=fmaxf(x,rorf<1>(x)); x=fmaxf(x,rorf<2>(x)); x=fmaxf(x,rorf<4>(x)); x=fmaxf(x,rorf<8>(x)); return x;
}
__device__ __forceinline__ float red16sum(float x){
  x+=rorf<1>(x); x+=rorf<2>(x); x+=rorf<4>(x); x+=rorf<8>(x); return x;
}
template<int C> __device__ __forceinline__ unsigned long long ror64(unsigned long long k){
  unsigned lo = (unsigned)__builtin_amdgcn_mov_dpp((int)(unsigned)k,        0x120|C, 0xF, 0xF, true);
  unsigned hi = (unsigned)__builtin_amdgcn_mov_dpp((int)(unsigned)(k>>32), 0x120|C, 0xF, 0xF, true);
  return ((unsigned long long)hi<<32)|lo;
}

// ---------------- fold: weight folding + BN precompute + bf16 weight converts ----------------
__global__ __launch_bounds__(256) void k_fold(P p) {
  int tid = blockIdx.x*256 + threadIdx.x;
  char* ws = p.ws;
  if (tid < 196608) {
    int m_id = tid >> 16, o = (tid >> 9) & 127, c = tid & 511;
    const float* A  = m_id==0 ? p.in[9] : (m_id==1 ? p.in[7] : p.in[11]);   // w_q / w_k / w_v
    const float* Bm = (m_id==0) ? p.in[3] : p.in[5];                        // w_sq / w_so
    float acc = 0.f;
    #pragma unroll 8
    for (int m=0;m<128;m++) acc += A[o*128+m] * Bm[m*512+c];
    bf16* outw = (bf16*)(ws + (m_id==0?OFF_WQS: m_id==1?OFF_WKO:OFF_WVO));
    outw[o*512+c] = (bf16)acc;
  } else if (tid < 196992) {
    int t = tid - 196608; int m_id = t >> 7, o = t & 127;
    const float* A  = m_id==0 ? p.in[9] : (m_id==1 ? p.in[7] : p.in[11]);
    const float* bb = (m_id==0) ? p.in[4] : p.in[6];
    const float* bs = m_id==0 ? p.in[10] : (m_id==1 ? p.in[8] : p.in[12]);
    float acc = bs[o];
    for (int m=0;m<128;m++) acc += A[o*128+m] * bb[m];
    float* ob = (float*)(ws + (m_id==0?OFF_BQS: m_id==1?OFF_BKO:OFF_BVO));
    ob[o] = acc;
  } else if (tid < 197056) {
    int i = tid - 196992;
    float s = p.in[15][i] * rsqrtf(p.in[18][i] + 1e-5f);
    ((float*)(ws+OFF_S1))[i] = s;
    ((float*)(ws+OFF_T1))[i] = (p.in[14][i] - p.in[17][i])*s + p.in[16][i];
  } else if (tid < 197568) {
    int i = tid - 197056;
    float s = p.in[23][i] * rsqrtf(p.in[26][i] + 1e-5f);
    ((float*)(ws+OFF_S2))[i] = s;
    ((float*)(ws+OFF_T2))[i] = (p.in[22][i] - p.in[25][i])*s + p.in[24][i];  // b_a1 folded
  } else if (tid < 223168) {
    int e0 = (tid - 197568) * 8;
    const float* src; int base;
    if (e0 < 8192)        { src = p.in[19]; base = 0; }        // w_p2
    else if (e0 < 73728)  { src = p.in[21]; base = 8192; }     // w_a1
    else if (e0 < 139264) { src = p.in[29]; base = 73728; }    // w_a2
    else                  { src = p.in[27]; base = 139264; }   // w_e
    const float* sp = src + (e0 - base);
    f32x4 a = *(const f32x4*)sp, b2 = *(const f32x4*)(sp+4);
    bf16x8 o8;
    o8[0]=(bf16)a[0]; o8[1]=(bf16)a[1]; o8[2]=(bf16)a[2]; o8[3]=(bf16)a[3];
    o8[4]=(bf16)b2[0]; o8[5]=(bf16)b2[1]; o8[6]=(bf16)b2[2]; o8[7]=(bf16)b2[3];
    *(bf16x8*)((bf16*)(ws+OFF_CW) + e0) = o8;
  }
}

// ---------------- merged knn + qkv (independent work, co-scheduled for pipe overlap) ----------------
__global__ __launch_bounds__(256) void k_knnqkv(P p) {
  if (blockIdx.x < 768) {
    // ---- qkv: [128,512]x[512,4096] GEMM -> [n][c] transposed outputs ----
    int qb = blockIdx.x;
    int mat = qb >> 8, b = (qb >> 6) & 3, n0 = (qb & 63) * 64;
    int tid = threadIdx.x, lane = tid&63, w = tid>>6;
    const float* in = (mat==0 ? p.in[2] : p.in[0]) + b*CIN*NPTS;
    const bf16* W = (const bf16*)(p.ws + (mat==0?OFF_WQS: mat==1?OFF_WKO:OFF_WVO));
    const float* bias = (const float*)(p.ws + (mat==0?OFF_BQS: mat==1?OFF_BKO:OFF_BVO));
    bf16* outT = (bf16*)(p.ws + (mat==0?OFF_QT: mat==1?OFF_KT:OFF_VT)) + (b*NPTS + n0)*DIM;
    __shared__ __align__(16) bf16 Bl[64*40];   // [64 n][32 c + 8 pad]
    f32x4 acc[8] = {};
    for (int ks=0; ks<16; ks++) {
      int c0 = ks*32;
      {
        int cc = tid>>3, nn0 = (tid&7)*8;
        const float* sp = in + (c0+cc)*NPTS + n0 + nn0;
        f32x4 a = *(const f32x4*)sp, b2 = *(const f32x4*)(sp+4);
        Bl[(nn0+0)*40+cc]=(bf16)a[0];  Bl[(nn0+1)*40+cc]=(bf16)a[1];
        Bl[(nn0+2)*40+cc]=(bf16)a[2];  Bl[(nn0+3)*40+cc]=(bf16)a[3];
        Bl[(nn0+4)*40+cc]=(bf16)b2[0]; Bl[(nn0+5)*40+cc]=(bf16)b2[1];
        Bl[(nn0+6)*40+cc]=(bf16)b2[2]; Bl[(nn0+7)*40+cc]=(bf16)b2[3];
      }
      __syncthreads();
      int ncol = w*16 + (lane&15);
      bf16x8 bfr = *(const bf16x8*)(&Bl[ncol*40 + (lane>>4)*8]);
      #pragma unroll
      for (int ot=0;ot<8;ot++) {
        bf16x8 af = *(const bf16x8*)(W + (ot*16 + (lane&15))*CIN + c0 + (lane>>4)*8);
        acc[ot] = MFMA16(af, bfr, acc[ot]);
      }
      __syncthreads();
    }
    int o0 = (lane>>4)*4;
    int nloc = w*16 + (lane&15);
    #pragma unroll
    for (int ot=0;ot<8;ot++) {
      f32x4 bs = *(const f32x4*)(bias + ot*16 + o0);
      bf16x4 st;
      st[0]=(bf16)(acc[ot][0]+bs[0]); st[1]=(bf16)(acc[ot][1]+bs[1]);
      st[2]=(bf16)(acc[ot][2]+bs[2]); st[3]=(bf16)(acc[ot][3]+bs[3]);
      *(bf16x4*)(outT + nloc*DIM + ot*16 + o0) = st;
    }
    return;
  }
  // ---- knn: cached chain minima; only the affected chain rescanned per round ----
  int lane = threadIdx.x & 63, w = threadIdx.x >> 6;
  int ig = (blockIdx.x - 768)*4 + w;       // b*4096 + n, covers 4*4096 points
  int b = ig >> 12, n = ig & 4095;
  const float* pb = p.in[1] + b*3*NPTS;
  float qx = pb[n], qy = pb[NPTS+n], qz = pb[2*NPTS+n];
  float sqn = __fadd_rn(__fadd_rn(__fmul_rn(qx,qx), __fmul_rn(qy,qy)), __fmul_rn(qz,qz));
  unsigned u[64];
  #pragma unroll
  for (int t=0;t<64;t++) {
    int j = t*64 + lane;
    float xj=pb[j], yj=pb[NPTS+j], zj=pb[2*NPTS+j];
    float sqj = __fadd_rn(__fadd_rn(__fmul_rn(xj,xj), __fmul_rn(yj,yj)), __fmul_rn(zj,zj));
    float dot = __fadd_rn(__fadd_rn(__fmul_rn(qx,xj), __fmul_rn(qy,yj)), __fmul_rn(qz,zj));
    float d2 = __fadd_rn(__fsub_rn(sqn, __fmul_rn(2.f,dot)), sqj);
    unsigned bb2 = __float_as_uint(d2);
    u[t] = bb2 ^ (((unsigned)((int)bb2 >> 31)) | 0x80000000u);   // order-preserving f32->u32
  }
  unsigned v0=u[0], v1=u[16], v2=u[32], v3=u[48];
  int t0=0, t1=16, t2=32, t3=48;
  #pragma unroll
  for (int i=1;i<16;i++) {
    { bool lt=u[i]    <v0; v0=lt?u[i]   :v0; t0=lt?(i)   :t0; }
    { bool lt=u[16+i] <v1; v1=lt?u[16+i]:v1; t1=lt?(16+i):t1; }
    { bool lt=u[32+i] <v2; v2=lt?u[32+i]:v2; t2=lt?(32+i):t2; }
    { bool lt=u[48+i] <v3; v3=lt?u[48+i]:v3; t3=lt?(48+i):t3; }
  }
  int* op = (int*)(p.ws + OFF_IDX) + ig*16;
  #pragma unroll 1
  for (int r=0;r<16;r++) {
    unsigned va=v0; int ta=t0;
    { bool lt=v1<va; va=lt?v1:va; ta=lt?t1:ta; }
    unsigned vb=v2; int tb=t2;
    { bool lt=v3<vb; vb=lt?v3:vb; tb=lt?t3:tb; }
    { bool lt=vb<va; va=lt?vb:va; ta=lt?tb:ta; }
    unsigned long long key = ((unsigned long long)va << 12) | (unsigned)((ta<<6) | lane);
    { unsigned long long o = ror64<1>(key); if (o<key) key=o; }
    { unsigned long long o = ror64<2>(key); if (o<key) key=o; }
    { unsigned long long o = ror64<4>(key); if (o<key) key=o; }
    { unsigned long long o = ror64<8>(key); if (o<key) key=o; }
    { unsigned long long o = __shfl_xor(key,16); if (o<key) key=o; }
    { unsigned long long o = __shfl_xor(key,32); if (o<key) key=o; }
    unsigned jwin = (unsigned)key & 4095u;
    if (lane==0) op[r] = (int)jwin;
    if (r==15) break;
    int tsel = __builtin_amdgcn_readfirstlane((int)(jwin>>6));
    bool mine = ((int)(jwin&63)==lane);
    switch (tsel) {
#define CLR(T) case T: u[T] = mine ? 0xFFFFFFFFu : u[T]; break;
      CLR(0) CLR(1) CLR(2) CLR(3) CLR(4) CLR(5) CLR(6) CLR(7)
      CLR(8) CLR(9) CLR(10) CLR(11) CLR(12) CLR(13) CLR(14) CLR(15)
      CLR(16) CLR(17) CLR(18) CLR(19) CLR(20) CLR(21) CLR(22) CLR(23)
      CLR(24) CLR(25) CLR(26) CLR(27) CLR(28) CLR(29) CLR(30) CLR(31)
      CLR(32) CLR(33) CLR(34) CLR(35) CLR(36) CLR(37) CLR(38) CLR(39)
      CLR(40) CLR(41) CLR(42) CLR(43) CLR(44) CLR(45) CLR(46) CLR(47)
      CLR(48) CLR(49) CLR(50) CLR(51) CLR(52) CLR(53) CLR(54) CLR(55)
      CLR(56) CLR(57) CLR(58) CLR(59) CLR(60) CLR(61) CLR(62) CLR(63)
#undef CLR
      default: break;
    }
    switch (tsel >> 4) {
      case 0: { v0=u[0]; t0=0;
        #pragma unroll
        for (int i=1;i<16;i++){ bool lt=u[i]<v0; v0=lt?u[i]:v0; t0=lt?i:t0; } } break;
      case 1: { v1=u[16]; t1=16;
        #pragma unroll
        for (int i=1;i<16;i++){ bool lt=u[16+i]<v1; v1=lt?u[16+i]:v1; t1=lt?(16+i):t1; } } break;
      case 2: { v2=u[32]; t2=32;
        #pragma unroll
        for (int i=1;i<16;i++){ bool lt=u[32+i]<v2; v2=lt?u[32+i]:v2; t2=lt?(32+i):t2; } } break;
      default: { v3=u[48]; t3=48;
        #pragma unroll
        for (int i=1;i<16;i++){ bool lt=u[48+i]<v3; v3=lt?u[48+i]:v3; t3=lt?(48+i):t3; } } break;
    }
  }
}

// ---------------- fused: per block = 1 batch x 4 points; 33.8K LDS, chunk=128, 11 barriers ----------------
__global__ __launch_bounds__(512) void k_fused(P p) {
  int bb = blockIdx.y, pt0 = blockIdx.x*4;
  int tid=threadIdx.x, lane=tid&63, w=tid>>6;
  int c = lane&15, g = lane>>4;
  char* ws = p.ws;
  const bf16* qT = (const bf16*)(ws+OFF_QT) + bb*NPTS*DIM;
  const bf16* kT = (const bf16*)(ws+OFF_KT) + bb*NPTS*DIM;
  const bf16* vT = (const bf16*)(ws+OFF_VT) + bb*NPTS*DIM;
  const int* idxg = (const int*)(ws+OFF_IDX) + (bb*NPTS + pt0)*16;
  const bf16* wp2b = (const bf16*)(ws+OFF_CW);
  const bf16* wa1b = wp2b + 8192;
  const bf16* wa2b = wa1b + 65536;
  const bf16* web  = wa2b + 65536;
  const float* s2 = (const float*)(ws+OFF_S2);
  const float* t2 = (const float*)(ws+OFF_T2);
  // arena: Xl [64 col][132] bf16 @0 (16896B); HT [64 col][132] bf16 @16896; aggl [4][132] overlays HT
  __shared__ __align__(16) char LB[33792];
  bf16* Xl = (bf16*)LB;
  bf16* HT = (bf16*)(LB + 16896);
  bf16* aggl = (bf16*)(LB + 16896);

  // phase 1: T1 = relu(bn1(w_p1 @ pos_rel)) -> HT[col][m]; lane=col, wave w -> m in [8w, 8w+8)
  {
    int col = lane;
    int j = idxg[col] & 4095;
    const float* pb = p.in[1] + bb*3*NPTS;
    int n = pt0 + (col>>4);
    float r0 = pb[n]-pb[j], r1 = pb[NPTS+n]-pb[NPTS+j], r2 = pb[2*NPTS+n]-pb[2*NPTS+j];
    const float* wp1 = p.in[13];
    const float* s1 = (const float*)(ws+OFF_S1);
    const float* t1 = (const float*)(ws+OFF_T1);
    bf16x4 o4[2];
    #pragma unroll
    for (int i=0;i<8;i++) {
      int m = w*8 + i;
      float x = wp1[m*3]*r0 + wp1[m*3+1]*r1 + wp1[m*3+2]*r2;
      o4[i>>2][i&3] = (bf16)fmaxf(0.f, x*s1[m] + t1[m]);
    }
    *(bf16x4*)(&HT[col*132 + w*8])     = o4[0];
    *(bf16x4*)(&HT[col*132 + w*8 + 4]) = o4[1];
  }
  __syncthreads();

  // phase 2: PE = w_p2 @ T1 + b_p2 ; X = q - k_g + PE -> Xl[col][chan]; wave w -> chans [16w,16w+16)
  {
    f32x4 acc[4] = {};
    int erow = w*16 + c;
    #pragma unroll
    for (int ksx=0; ksx<2; ksx++) {
      int m0 = ksx*32 + g*8;
      bf16x8 af = *(const bf16x8*)(wp2b + erow*PH + m0);
      #pragma unroll
      for (int ct=0; ct<4; ct++) {
        bf16x8 bfr = *(const bf16x8*)(&HT[(ct*16+c)*132 + m0]);
        acc[ct] = MFMA16(af, bfr, acc[ct]);
      }
    }
    int c0 = w*16 + g*4;
    f32x4 bp4 = *(const f32x4*)(p.in[20] + c0);
    #pragma unroll
    for (int ct=0; ct<4; ct++) {
      int col = ct*16 + c;
      int j = idxg[col] & 4095;
      int n = pt0 + ct;
      bf16x4 q4 = *(const bf16x4*)(qT + n*DIM + c0);
      bf16x4 k4 = *(const bf16x4*)(kT + j*DIM + c0);
      bf16x4 st;
      #pragma unroll
      for (int r=0;r<4;r++)
        st[r] = (bf16)((float)q4[r] - (float)k4[r] + acc[ct][r] + bp4[r]);
      *(bf16x4*)(&Xl[col*132 + c0]) = st;
    }
  }
  __syncthreads();

  // phase 3: fused MLP, 4 chunks of 128 hidden; wave = 32h x 32c (G1) and 32o x 32c (G2)
  int wh = w >> 1, wc1 = w & 1;
  f32x4 S[2][2] = {{{},{}},{{},{}}};
  for (int ch=0; ch<4; ch++) {
    f32x4 a1[2][2] = {{{},{}},{{},{}}};
    #pragma unroll
    for (int ksx=0; ksx<4; ksx++) {
      int k0 = ksx*32 + g*8;
      bf16x8 af0 = *(const bf16x8*)(wa1b + (ch*128 + wh*32 + c)*DIM + k0);
      bf16x8 af1 = *(const bf16x8*)(wa1b + (ch*128 + wh*32 + 16 + c)*DIM + k0);
      bf16x8 b0  = *(const bf16x8*)(&Xl[(wc1*32 + c)*132 + k0]);
      bf16x8 b1  = *(const bf16x8*)(&Xl[(wc1*32 + 16 + c)*132 + k0]);
      a1[0][0] = MFMA16(af0, b0, a1[0][0]);
      a1[0][1] = MFMA16(af0, b1, a1[0][1]);
      a1[1][0] = MFMA16(af1, b0, a1[1][0]);
      a1[1][1] = MFMA16(af1, b1, a1[1][1]);
    }
    #pragma unroll
    for (int i2=0;i2<2;i2++) {
      int hl = wh*32 + i2*16 + g*4;
      int hg = ch*128 + hl;
      f32x4 sv = *(const f32x4*)(s2 + hg);
      f32x4 tv = *(const f32x4*)(t2 + hg);
      #pragma unroll
      for (int j2=0;j2<2;j2++) {
        int col = wc1*32 + j2*16 + c;
        bf16x4 st;
        st[0]=(bf16)fmaxf(0.f, a1[i2][j2][0]*sv[0]+tv[0]);
        st[1]=(bf16)fmaxf(0.f, a1[i2][j2][1]*sv[1]+tv[1]);
        st[2]=(bf16)fmaxf(0.f, a1[i2][j2][2]*sv[2]+tv[2]);
        st[3]=(bf16)fmaxf(0.f, a1[i2][j2][3]*sv[3]+tv[3]);
        *(bf16x4*)(&HT[col*132 + hl]) = st;
      }
    }
    __syncthreads();
    #pragma unroll
    for (int ksg=0; ksg<4; ksg++) {
      int k0 = ksg*32 + g*8;
      bf16x8 af0 = *(const bf16x8*)(wa2b + (wh*32 + c)*HID + ch*128 + k0);
      bf16x8 af1 = *(const bf16x8*)(wa2b + (wh*32 + 16 + c)*HID + ch*128 + k0);
      bf16x8 b0  = *(const bf16x8*)(&HT[(wc1*32 + c)*132 + k0]);
      bf16x8 b1  = *(const bf16x8*)(&HT[(wc1*32 + 16 + c)*132 + k0]);
      S[0][0] = MFMA16(af0, b0, S[0][0]);
      S[0][1] = MFMA16(af0, b1, S[0][1]);
      S[1][0] = MFMA16(af1, b0, S[1][0]);
      S[1][1] = MFMA16(af1, b1, S[1][1]);
    }
    __syncthreads();
  }

  // phase 4: softmax over k (16 lanes, DPP) + agg -> aggl (overlays dead HT)
  #pragma unroll
  for (int i2=0;i2<2;i2++) {
    #pragma unroll
    for (int j2=0;j2<2;j2++) {
      int ptl = wc1*2 + j2;
      int colg = ptl*16 + c;
      int j = idxg[colg] & 4095;
      int n = pt0 + ptl;
      int chb = wh*32 + i2*16 + g*4;
      bf16x4 x4 = *(const bf16x4*)(&Xl[colg*132 + chb]);
      bf16x4 q4 = *(const bf16x4*)(qT + n*DIM + chb);
      bf16x4 k4 = *(const bf16x4*)(kT + j*DIM + chb);
      bf16x4 v4 = *(const bf16x4*)(vT + n*DIM + chb);
      float agv[4];
      #pragma unroll
      for (int r=0;r<4;r++) {
        float s = S[i2][j2][r];
        float mx = red16max(s);
        float e = __expf(s-mx);
        float sm = red16sum(e);
        float at = e/sm;
        float vpe = (float)v4[r] + (float)x4[r] - (float)q4[r] + (float)k4[r];
        agv[r] = red16sum(at*vpe);
      }
      if (c==0) {
        bf16x4 st; st[0]=(bf16)agv[0]; st[1]=(bf16)agv[1]; st[2]=(bf16)agv[2]; st[3]=(bf16)agv[3];
        *(bf16x4*)(&aggl[ptl*132 + chb]) = st;
      }
    }
  }
  __syncthreads();

  // phase 5: out = w_e @ agg + b_e (B cols 4..15 read finite in-arena garbage; their C cols discarded)
  {
    const float* be = p.in[28];
    f32x4 acc5[4] = {};
    #pragma unroll
    for (int ksx=0; ksx<4; ksx++) {
      bf16x8 bfr = *(const bf16x8*)(&aggl[c*132 + ksx*32 + g*8]);
      #pragma unroll
      for (int i=0;i<4;i++) {
        int e = (w*4+i)*16 + c;
        bf16x8 af = *(const bf16x8*)(web + e*DIM + ksx*32 + g*8);
        acc5[i] = MFMA16(af, bfr, acc5[i]);
      }
    }
    if (c < 4) {
      int n = pt0 + c;
      #pragma unroll
      for (int i=0;i<4;i++) {
        int e0 = (w*4+i)*16 + g*4;
        f32x4 be4 = *(const f32x4*)(be + e0);
        #pragma unroll
        for (int r=0;r<4;r++)
          p.out[(bb*CIN + e0+r)*NPTS + n] = acc5[i][r] + be4[r];
      }
    }
  }
}

extern "C" void kernel_launch(void* const* d_in, const int* in_sizes, int n_in,
                              void* d_out, int out_size, void* d_ws, size_t ws_size,
                              hipStream_t stream) {
  if (ws_size < WS_NEED || n_in < 31) return;  // loud failure: output stays zero
  P p;
  for (int i=0;i<31;i++) p.in[i] = (const float*)d_in[i];
  p.ws = (char*)d_ws;
  p.out = (float*)d_out;
  p.ybase = 0;
  k_fold<<<872, 256, 0, stream>>>(p);
  k_knnqkv<<<768 + 4096, 256, 0, stream>>>(p);   // 768 qkv blocks + 4096 knn blocks (16384 waves)
  k_fused<<<dim3(1024, 4), 512, 0, stream>>>(p);
}

// Round 13
// 404.132 us; speedup vs baseline: 1.4456x; 1.4456x over previous
//
#include <hip/hip_runtime.h>

typedef __bf16 bf16;
typedef __bf16 bf16x8 __attribute__((ext_vector_type(8)));
typedef __bf16 bf16x4 __attribute__((ext_vector_type(4)));
typedef __bf16 bf16x2 __attribute__((ext_vector_type(2)));
typedef float f32x4 __attribute__((ext_vector_type(4)));

#define MFMA16(a,b,c) __builtin_amdgcn_mfma_f32_16x16x32_bf16((a),(b),(c),0,0,0)

#define NPTS 4096
#define CIN 512
#define DIM 128
#define PH 64
#define HID 512

// ws layout (bytes)
#define OFF_WQS 0u                  // bf16 [128][512] folded w_q@w_sq
#define OFF_WKO (128u*1024u)        // bf16 [128][512] folded w_k@w_so
#define OFF_WVO (256u*1024u)        // bf16 [128][512] folded w_v@w_so
#define OFF_BQS (384u*1024u)        // f32 [128]
#define OFF_BKO (385u*1024u)
#define OFF_BVO (386u*1024u)
#define OFF_S1  (387u*1024u)        // f32 [64]
#define OFF_T1  (388u*1024u)
#define OFF_S2  (389u*1024u)        // f32 [512]
#define OFF_T2  (391u*1024u)        // f32 [512]
#define OFF_CW  (400u*1024u)        // bf16 [wp2 8192 | wa1 65536 | wa2 65536 | we 65536]
#define OFF_QT  (1u<<20)            // bf16 [B][4096][128]
#define OFF_KT  (OFF_QT + (4u<<20))
#define OFF_VT  (OFF_QT + (8u<<20))
#define OFF_IDX (OFF_QT + (12u<<20))
#define WS_NEED (OFF_QT + (13u<<20))

struct P {
  const float* in[31];
  char* ws;
  float* out;
  int ybase;
};

template<int C> __device__ __forceinline__ float rorf(float x){
  return __int_as_float(__builtin_amdgcn_mov_dpp(__float_as_int(x), 0x120|C, 0xF, 0xF, true));
}
__device__ __forceinline__ float red16max(float x){
  x=fmaxf(x,rorf<1>(x)); x=fmaxf(x,rorf<2>(x)); x=fmaxf(x,rorf<4>(x)); x=fmaxf(x,rorf<8>(x)); return x;
}
__device__ __forceinline__ float red16sum(float x){
  x+=rorf<1>(x); x+=rorf<2>(x); x+=rorf<4>(x); x+=rorf<8>(x); return x;
}
template<int C> __device__ __forceinline__ unsigned long long ror64(unsigned long long k){
  unsigned lo = (unsigned)__builtin_amdgcn_mov_dpp((int)(unsigned)k,        0x120|C, 0xF, 0xF, true);
  unsigned hi = (unsigned)__builtin_amdgcn_mov_dpp((int)(unsigned)(k>>32), 0x120|C, 0xF, 0xF, true);
  return ((unsigned long long)hi<<32)|lo;
}

// ---------------- fold: weight folding + BN precompute + bf16 weight converts ----------------
__global__ __launch_bounds__(256) void k_fold(P p) {
  int tid = blockIdx.x*256 + threadIdx.x;
  char* ws = p.ws;
  if (tid < 196608) {
    int m_id = tid >> 16, o = (tid >> 9) & 127, c = tid & 511;
    const float* A  = m_id==0 ? p.in[9] : (m_id==1 ? p.in[7] : p.in[11]);   // w_q / w_k / w_v
    const float* Bm = (m_id==0) ? p.in[3] : p.in[5];                        // w_sq / w_so
    float acc = 0.f;
    #pragma unroll 8
    for (int m=0;m<128;m++) acc += A[o*128+m] * Bm[m*512+c];
    bf16* outw = (bf16*)(ws + (m_id==0?OFF_WQS: m_id==1?OFF_WKO:OFF_WVO));
    outw[o*512+c] = (bf16)acc;
  } else if (tid < 196992) {
    int t = tid - 196608; int m_id = t >> 7, o = t & 127;
    const float* A  = m_id==0 ? p.in[9] : (m_id==1 ? p.in[7] : p.in[11]);
    const float* bb = (m_id==0) ? p.in[4] : p.in[6];
    const float* bs = m_id==0 ? p.in[10] : (m_id==1 ? p.in[8] : p.in[12]);
    float acc = bs[o];
    for (int m=0;m<128;m++) acc += A[o*128+m] * bb[m];
    float* ob = (float*)(ws + (m_id==0?OFF_BQS: m_id==1?OFF_BKO:OFF_BVO));
    ob[o] = acc;
  } else if (tid < 197056) {
    int i = tid - 196992;
    float s = p.in[15][i] * rsqrtf(p.in[18][i] + 1e-5f);
    ((float*)(ws+OFF_S1))[i] = s;
    ((float*)(ws+OFF_T1))[i] = (p.in[14][i] - p.in[17][i])*s + p.in[16][i];
  } else if (tid < 197568) {
    int i = tid - 197056;
    float s = p.in[23][i] * rsqrtf(p.in[26][i] + 1e-5f);
    ((float*)(ws+OFF_S2))[i] = s;
    ((float*)(ws+OFF_T2))[i] = (p.in[22][i] - p.in[25][i])*s + p.in[24][i];  // b_a1 folded
  } else if (tid < 223168) {
    int e0 = (tid - 197568) * 8;
    const float* src; int base;
    if (e0 < 8192)        { src = p.in[19]; base = 0; }        // w_p2
    else if (e0 < 73728)  { src = p.in[21]; base = 8192; }     // w_a1
    else if (e0 < 139264) { src = p.in[29]; base = 73728; }    // w_a2
    else                  { src = p.in[27]; base = 139264; }   // w_e
    const float* sp = src + (e0 - base);
    f32x4 a = *(const f32x4*)sp, b2 = *(const f32x4*)(sp+4);
    bf16x8 o8;
    o8[0]=(bf16)a[0]; o8[1]=(bf16)a[1]; o8[2]=(bf16)a[2]; o8[3]=(bf16)a[3];
    o8[4]=(bf16)b2[0]; o8[5]=(bf16)b2[1]; o8[6]=(bf16)b2[2]; o8[7]=(bf16)b2[3];
    *(bf16x8*)((bf16*)(ws+OFF_CW) + e0) = o8;
  }
}

// ---------------- merged knn + qkv (independent work, co-scheduled for pipe overlap) ----------------
__global__ __launch_bounds__(256) void k_knnqkv(P p) {
  if (blockIdx.x < 768) {
    // ---- qkv: [128,512]x[512,4096] GEMM -> [n][c] transposed outputs ----
    int qb = blockIdx.x;
    int mat = qb >> 8, b = (qb >> 6) & 3, n0 = (qb & 63) * 64;
    int tid = threadIdx.x, lane = tid&63, w = tid>>6;
    const float* in = (mat==0 ? p.in[2] : p.in[0]) + b*CIN*NPTS;
    const bf16* W = (const bf16*)(p.ws + (mat==0?OFF_WQS: mat==1?OFF_WKO:OFF_WVO));
    const float* bias = (const float*)(p.ws + (mat==0?OFF_BQS: mat==1?OFF_BKO:OFF_BVO));
    bf16* outT = (bf16*)(p.ws + (mat==0?OFF_QT: mat==1?OFF_KT:OFF_VT)) + (b*NPTS + n0)*DIM;
    __shared__ __align__(16) bf16 Bl[64*40];   // [64 n][32 c + 8 pad]
    f32x4 acc[8] = {};
    for (int ks=0; ks<16; ks++) {
      int c0 = ks*32;
      {
        int cc = tid>>3, nn0 = (tid&7)*8;
        const float* sp = in + (c0+cc)*NPTS + n0 + nn0;
        f32x4 a = *(const f32x4*)sp, b2 = *(const f32x4*)(sp+4);
        Bl[(nn0+0)*40+cc]=(bf16)a[0];  Bl[(nn0+1)*40+cc]=(bf16)a[1];
        Bl[(nn0+2)*40+cc]=(bf16)a[2];  Bl[(nn0+3)*40+cc]=(bf16)a[3];
        Bl[(nn0+4)*40+cc]=(bf16)b2[0]; Bl[(nn0+5)*40+cc]=(bf16)b2[1];
        Bl[(nn0+6)*40+cc]=(bf16)b2[2]; Bl[(nn0+7)*40+cc]=(bf16)b2[3];
      }
      __syncthreads();
      int ncol = w*16 + (lane&15);
      bf16x8 bfr = *(const bf16x8*)(&Bl[ncol*40 + (lane>>4)*8]);
      #pragma unroll
      for (int ot=0;ot<8;ot++) {
        bf16x8 af = *(const bf16x8*)(W + (ot*16 + (lane&15))*CIN + c0 + (lane>>4)*8);
        acc[ot] = MFMA16(af, bfr, acc[ot]);
      }
      __syncthreads();
    }
    int o0 = (lane>>4)*4;
    int nloc = w*16 + (lane&15);
    #pragma unroll
    for (int ot=0;ot<8;ot++) {
      f32x4 bs = *(const f32x4*)(bias + ot*16 + o0);
      bf16x4 st;
      st[0]=(bf16)(acc[ot][0]+bs[0]); st[1]=(bf16)(acc[ot][1]+bs[1]);
      st[2]=(bf16)(acc[ot][2]+bs[2]); st[3]=(bf16)(acc[ot][3]+bs[3]);
      *(bf16x4*)(outT + nloc*DIM + ot*16 + o0) = st;
    }
    return;
  }
  // ---- knn: cached chain minima; only the affected chain rescanned per round ----
  int lane = threadIdx.x & 63, w = threadIdx.x >> 6;
  int ig = (blockIdx.x - 768)*4 + w;       // b*4096 + n, covers 4*4096 points
  int b = ig >> 12, n = ig & 4095;
  const float* pb = p.in[1] + b*3*NPTS;
  float qx = pb[n], qy = pb[NPTS+n], qz = pb[2*NPTS+n];
  float sqn = __fadd_rn(__fadd_rn(__fmul_rn(qx,qx), __fmul_rn(qy,qy)), __fmul_rn(qz,qz));
  unsigned u[64];
  #pragma unroll
  for (int t=0;t<64;t++) {
    int j = t*64 + lane;
    float xj=pb[j], yj=pb[NPTS+j], zj=pb[2*NPTS+j];
    float sqj = __fadd_rn(__fadd_rn(__fmul_rn(xj,xj), __fmul_rn(yj,yj)), __fmul_rn(zj,zj));
    float dot = __fadd_rn(__fadd_rn(__fmul_rn(qx,xj), __fmul_rn(qy,yj)), __fmul_rn(qz,zj));
    float d2 = __fadd_rn(__fsub_rn(sqn, __fmul_rn(2.f,dot)), sqj);
    unsigned bb2 = __float_as_uint(d2);
    u[t] = bb2 ^ (((unsigned)((int)bb2 >> 31)) | 0x80000000u);   // order-preserving f32->u32
  }
  unsigned v0=u[0], v1=u[16], v2=u[32], v3=u[48];
  int t0=0, t1=16, t2=32, t3=48;
  #pragma unroll
  for (int i=1;i<16;i++) {
    { bool lt=u[i]    <v0; v0=lt?u[i]   :v0; t0=lt?(i)   :t0; }
    { bool lt=u[16+i] <v1; v1=lt?u[16+i]:v1; t1=lt?(16+i):t1; }
    { bool lt=u[32+i] <v2; v2=lt?u[32+i]:v2; t2=lt?(32+i):t2; }
    { bool lt=u[48+i] <v3; v3=lt?u[48+i]:v3; t3=lt?(48+i):t3; }
  }
  int* op = (int*)(p.ws + OFF_IDX) + ig*16;
  #pragma unroll 1
  for (int r=0;r<16;r++) {
    unsigned va=v0; int ta=t0;
    { bool lt=v1<va; va=lt?v1:va; ta=lt?t1:ta; }
    unsigned vb=v2; int tb=t2;
    { bool lt=v3<vb; vb=lt?v3:vb; tb=lt?t3:tb; }
    { bool lt=vb<va; va=lt?vb:va; ta=lt?tb:ta; }
    unsigned long long key = ((unsigned long long)va << 12) | (unsigned)((ta<<6) | lane);
    { unsigned long long o = ror64<1>(key); if (o<key) key=o; }
    { unsigned long long o = ror64<2>(key); if (o<key) key=o; }
    { unsigned long long o = ror64<4>(key); if (o<key) key=o; }
    { unsigned long long o = ror64<8>(key); if (o<key) key=o; }
    { unsigned long long o = __shfl_xor(key,16); if (o<key) key=o; }
    { unsigned long long o = __shfl_xor(key,32); if (o<key) key=o; }
    unsigned jwin = (unsigned)key & 4095u;
    if (lane==0) op[r] = (int)jwin;
    if (r==15) break;
    int tsel = __builtin_amdgcn_readfirstlane((int)(jwin>>6));
    bool mine = ((int)(jwin&63)==lane);
    switch (tsel) {
#define CLR(T) case T: u[T] = mine ? 0xFFFFFFFFu : u[T]; break;
      CLR(0) CLR(1) CLR(2) CLR(3) CLR(4) CLR(5) CLR(6) CLR(7)
      CLR(8) CLR(9) CLR(10) CLR(11) CLR(12) CLR(13) CLR(14) CLR(15)
      CLR(16) CLR(17) CLR(18) CLR(19) CLR(20) CLR(21) CLR(22) CLR(23)
      CLR(24) CLR(25) CLR(26) CLR(27) CLR(28) CLR(29) CLR(30) CLR(31)
      CLR(32) CLR(33) CLR(34) CLR(35) CLR(36) CLR(37) CLR(38) CLR(39)
      CLR(40) CLR(41) CLR(42) CLR(43) CLR(44) CLR(45) CLR(46) CLR(47)
      CLR(48) CLR(49) CLR(50) CLR(51) CLR(52) CLR(53) CLR(54) CLR(55)
      CLR(56) CLR(57) CLR(58) CLR(59) CLR(60) CLR(61) CLR(62) CLR(63)
#undef CLR
      default: break;
    }
    switch (tsel >> 4) {
      case 0: { v0=u[0]; t0=0;
        #pragma unroll
        for (int i=1;i<16;i++){ bool lt=u[i]<v0; v0=lt?u[i]:v0; t0=lt?i:t0; } } break;
      case 1: { v1=u[16]; t1=16;
        #pragma unroll
        for (int i=1;i<16;i++){ bool lt=u[16+i]<v1; v1=lt?u[16+i]:v1; t1=lt?(16+i):t1; } } break;
      case 2: { v2=u[32]; t2=32;
        #pragma unroll
        for (int i=1;i<16;i++){ bool lt=u[32+i]<v2; v2=lt?u[32+i]:v2; t2=lt?(32+i):t2; } } break;
      default: { v3=u[48]; t3=48;
        #pragma unroll
        for (int i=1;i<16;i++){ bool lt=u[48+i]<v3; v3=lt?u[48+i]:v3; t3=lt?(48+i):t3; } } break;
    }
  }
}

// ---------------- fused: per block = 1 batch x 8 points; LDS 53.2K (R8 structure, best measured) ----------------
__global__ __launch_bounds__(512) void k_fused(P p) {
  int bb = p.ybase + blockIdx.y, pt0 = blockIdx.x*8;
  int tid=threadIdx.x, lane=tid&63, w=tid>>6;
  int c = lane&15, g = lane>>4;
  char* ws = p.ws;
  const bf16* qT = (const bf16*)(ws+OFF_QT) + bb*NPTS*DIM;
  const bf16* kT = (const bf16*)(ws+OFF_KT) + bb*NPTS*DIM;
  const bf16* vT = (const bf16*)(ws+OFF_VT) + bb*NPTS*DIM;
  const int* idxg = (const int*)(ws+OFF_IDX) + (bb*NPTS + pt0)*16;
  const bf16* wp2b = (const bf16*)(ws+OFF_CW);
  const bf16* wa1b = wp2b + 8192;
  const bf16* wa2b = wa1b + 65536;
  const bf16* web  = wa2b + 65536;
  const float* s2 = (const float*)(ws+OFF_S2);
  const float* t2 = (const float*)(ws+OFF_T2);
  __shared__ __align__(16) char LB[53248];
  bf16* Xl = (bf16*)LB;            // [128 col][136]
  bf16* HT = (bf16*)(LB + 34816);  // [128 col][72]
  bf16* aggl = (bf16*)(LB + 34816);// [<=16 pt][136] overlays dead HT

  // phase 1: T1 = relu(bn1(w_p1 @ pos_rel)) -> HT[col][m]
  {
    int col = w*16 + c;
    int j = idxg[col] & 4095;
    const float* pb = p.in[1] + bb*3*NPTS;
    int n = pt0 + w;
    float r0 = pb[n]-pb[j], r1 = pb[NPTS+n]-pb[NPTS+j], r2 = pb[2*NPTS+n]-pb[2*NPTS+j];
    const float* wp1 = p.in[13];
    const float* s1 = (const float*)(ws+OFF_S1);
    const float* t1 = (const float*)(ws+OFF_T1);
    #pragma unroll
    for (int i=0;i<16;i+=2) {
      int m = g*16 + i;
      float x0 = wp1[m*3]*r0   + wp1[m*3+1]*r1 + wp1[m*3+2]*r2;
      float x1 = wp1[m*3+3]*r0 + wp1[m*3+4]*r1 + wp1[m*3+5]*r2;
      bf16x2 pk;
      pk[0] = (bf16)fmaxf(0.f, x0*s1[m]   + t1[m]);
      pk[1] = (bf16)fmaxf(0.f, x1*s1[m+1] + t1[m+1]);
      *(bf16x2*)(&HT[col*72 + m]) = pk;
    }
  }
  __syncthreads();

  // phase 2: PE = w_p2 @ T1 + b_p2 ; X = q - k_g + PE -> Xl[col][c]
  {
    f32x4 acc[8] = {};
    int crow = w*16 + c;
    #pragma unroll
    for (int ksx=0; ksx<2; ksx++) {
      int m0 = ksx*32 + g*8;
      bf16x8 af = *(const bf16x8*)(wp2b + crow*PH + m0);
      #pragma unroll
      for (int nt=0; nt<8; nt++) {
        int col = nt*16 + c;
        bf16x8 bfr = *(const bf16x8*)(&HT[col*72 + m0]);
        acc[nt] = MFMA16(af, bfr, acc[nt]);
      }
    }
    int c0 = w*16 + g*4;
    f32x4 bp4 = *(const f32x4*)(p.in[20] + c0);
    #pragma unroll
    for (int nt=0; nt<8; nt++) {
      int col = nt*16 + c;
      int j = idxg[col] & 4095;
      int n = pt0 + nt;
      bf16x4 q4 = *(const bf16x4*)(qT + n*DIM + c0);
      bf16x4 k4 = *(const bf16x4*)(kT + j*DIM + c0);
      bf16x4 st;
      #pragma unroll
      for (int r=0;r<4;r++)
        st[r] = (bf16)((float)q4[r] - (float)k4[r] + acc[nt][r] + bp4[r]);
      *(bf16x4*)(&Xl[col*136 + c0]) = st;
    }
  }
  __syncthreads();

  // phase 3: fused MLP, 8 chunks of 64 hidden rows
  f32x4 S[8] = {};
  for (int ch=0; ch<8; ch++) {
    f32x4 acc1[4] = {};
    int mtw = w & 3, nbase = (w>>2)*4;
    int hrow = ch*64 + mtw*16 + c;
    #pragma unroll
    for (int ksx=0; ksx<4; ksx++) {
      bf16x8 af = *(const bf16x8*)(wa1b + hrow*DIM + ksx*32 + g*8);
      #pragma unroll
      for (int i=0; i<4; i++) {
        int col = (nbase+i)*16 + c;
        bf16x8 bfr = *(const bf16x8*)(&Xl[col*136 + ksx*32 + g*8]);
        acc1[i] = MFMA16(af, bfr, acc1[i]);
      }
    }
    int h0 = ch*64 + mtw*16 + g*4;
    int h0loc = mtw*16 + g*4;
    f32x4 sv = *(const f32x4*)(s2 + h0);
    f32x4 tv = *(const f32x4*)(t2 + h0);
    #pragma unroll
    for (int i=0;i<4;i++) {
      int col = (nbase+i)*16 + c;
      bf16x4 st;
      st[0]=(bf16)fmaxf(0.f, acc1[i][0]*sv[0]+tv[0]);
      st[1]=(bf16)fmaxf(0.f, acc1[i][1]*sv[1]+tv[1]);
      st[2]=(bf16)fmaxf(0.f, acc1[i][2]*sv[2]+tv[2]);
      st[3]=(bf16)fmaxf(0.f, acc1[i][3]*sv[3]+tv[3]);
      *(bf16x4*)(&HT[col*72 + h0loc]) = st;
    }
    __syncthreads();
    int orow = w*16 + c;
    #pragma unroll
    for (int ksx=0; ksx<2; ksx++) {
      bf16x8 af = *(const bf16x8*)(wa2b + orow*HID + ch*64 + ksx*32 + g*8);
      #pragma unroll
      for (int nt=0; nt<8; nt++) {
        int col = nt*16 + c;
        bf16x8 bfr = *(const bf16x8*)(&HT[col*72 + ksx*32 + g*8]);
        S[nt] = MFMA16(af, bfr, S[nt]);
      }
    }
    __syncthreads();
  }

  // phase 4: softmax over k (16 lanes, DPP) + agg -> aggl (overlays dead HT)
  {
    int c0 = w*16 + g*4;
    #pragma unroll
    for (int nt=0; nt<8; nt++) {
      f32x4 s = S[nt];
      int col = nt*16 + c;
      int j = idxg[col] & 4095;
      int n = pt0 + nt;
      bf16x4 x4 = *(const bf16x4*)(&Xl[col*136 + c0]);
      bf16x4 q4 = *(const bf16x4*)(qT + n*DIM + c0);
      bf16x4 k4 = *(const bf16x4*)(kT + j*DIM + c0);
      bf16x4 v4 = *(const bf16x4*)(vT + n*DIM + c0);
      float agv[4];
      #pragma unroll
      for (int r=0;r<4;r++) {
        float mx = red16max(s[r]);
        float e = __expf(s[r]-mx);
        float sm = red16sum(e);
        float at = e/sm;
        float vpe = (float)v4[r] + (float)x4[r] - (float)q4[r] + (float)k4[r];
        agv[r] = red16sum(at*vpe);
      }
      if (c==0) {
        bf16x4 st; st[0]=(bf16)agv[0]; st[1]=(bf16)agv[1]; st[2]=(bf16)agv[2]; st[3]=(bf16)agv[3];
        *(bf16x4*)(&aggl[nt*136 + c0]) = st;
      }
    }
  }
  __syncthreads();

  // phase 5: out = w_e @ agg + b_e
  {
    const float* be = p.in[28];
    f32x4 acc5[4] = {};
    #pragma unroll
    for (int ksx=0; ksx<4; ksx++) {
      bf16x8 bfr = *(const bf16x8*)(&aggl[c*136 + ksx*32 + g*8]);
      #pragma unroll
      for (int i=0;i<4;i++) {
        int e = (w*4+i)*16 + c;
        bf16x8 af = *(const bf16x8*)(web + e*DIM + ksx*32 + g*8);
        acc5[i] = MFMA16(af, bfr, acc5[i]);
      }
    }
    if (c < 8) {
      int n = pt0 + c;
      #pragma unroll
      for (int i=0;i<4;i++) {
        int e0 = (w*4+i)*16 + g*4;
        f32x4 be4 = *(const f32x4*)(be + e0);
        #pragma unroll
        for (int r=0;r<4;r++)
          p.out[(bb*CIN + e0+r)*NPTS + n] = acc5[i][r] + be4[r];
      }
    }
  }
}

extern "C" void kernel_launch(void* const* d_in, const int* in_sizes, int n_in,
                              void* d_out, int out_size, void* d_ws, size_t ws_size,
                              hipStream_t stream) {
  if (ws_size < WS_NEED || n_in < 31) return;  // loud failure: output stays zero
  P p;
  for (int i=0;i<31;i++) p.in[i] = (const float*)d_in[i];
  p.ws = (char*)d_ws;
  p.out = (float*)d_out;
  p.ybase = 0;
  k_fold<<<872, 256, 0, stream>>>(p);
  k_knnqkv<<<768 + 4096, 256, 0, stream>>>(p);   // 768 qkv blocks + 4096 knn blocks
  k_fused<<<dim3(512, 4), 512, 0, stream>>>(p);
}

// Round 14
// 400.325 us; speedup vs baseline: 1.4593x; 1.0095x over previous
//
#include <hip/hip_runtime.h>

typedef __bf16 bf16;
typedef __bf16 bf16x8 __attribute__((ext_vector_type(8)));
typedef __bf16 bf16x4 __attribute__((ext_vector_type(4)));
typedef __bf16 bf16x2 __attribute__((ext_vector_type(2)));
typedef float f32x4 __attribute__((ext_vector_type(4)));

#define MFMA16(a,b,c) __builtin_amdgcn_mfma_f32_16x16x32_bf16((a),(b),(c),0,0,0)

#define NPTS 4096
#define CIN 512
#define DIM 128
#define PH 64
#define HID 512

// ws layout (bytes)
#define OFF_WQS 0u                  // bf16 [128][512] folded w_q@w_sq
#define OFF_WKO (128u*1024u)        // bf16 [128][512] folded w_k@w_so
#define OFF_WVO (256u*1024u)        // bf16 [128][512] folded w_v@w_so
#define OFF_BQS (384u*1024u)        // f32 [128]
#define OFF_BKO (385u*1024u)
#define OFF_BVO (386u*1024u)
#define OFF_S1  (387u*1024u)        // f32 [64]
#define OFF_T1  (388u*1024u)
#define OFF_S2  (389u*1024u)        // f32 [512]
#define OFF_T2  (391u*1024u)        // f32 [512]
#define OFF_CW  (400u*1024u)        // bf16 [wp2 8192 | wa1 65536 | wa2 65536 | we 65536]
#define OFF_QT  (1u<<20)            // bf16 [B][4096][128]
#define OFF_KT  (OFF_QT + (4u<<20))
#define OFF_VT  (OFF_QT + (8u<<20))
#define OFF_IDX (OFF_QT + (12u<<20))
#define WS_NEED (OFF_QT + (13u<<20))

struct P {
  const float* in[31];
  char* ws;
  float* out;
  int ybase;
};

// barrier WITHOUT the compiler's vmcnt(0) drain: LDS handoffs need lgkm only;
// read-only global loads stay in flight (consumer-waited at use).
__device__ __forceinline__ void softbar() {
  asm volatile("s_waitcnt lgkmcnt(0)" ::: "memory");
  __builtin_amdgcn_s_barrier();
  __builtin_amdgcn_sched_barrier(0);
}

template<int C> __device__ __forceinline__ float rorf(float x){
  return __int_as_float(__builtin_amdgcn_mov_dpp(__float_as_int(x), 0x120|C, 0xF, 0xF, true));
}
__device__ __forceinline__ float red16max(float x){
  x=fmaxf(x,rorf<1>(x)); x=fmaxf(x,rorf<2>(x)); x=fmaxf(x,rorf<4>(x)); x=fmaxf(x,rorf<8>(x)); return x;
}
__device__ __forceinline__ float red16sum(float x){
  x+=rorf<1>(x); x+=rorf<2>(x); x+=rorf<4>(x); x+=rorf<8>(x); return x;
}
template<int C> __device__ __forceinline__ unsigned long long ror64(unsigned long long k){
  unsigned lo = (unsigned)__builtin_amdgcn_mov_dpp((int)(unsigned)k,        0x120|C, 0xF, 0xF, true);
  unsigned hi = (unsigned)__builtin_amdgcn_mov_dpp((int)(unsigned)(k>>32), 0x120|C, 0xF, 0xF, true);
  return ((unsigned long long)hi<<32)|lo;
}

// ---------------- fold: weight folding + BN precompute + bf16 weight converts ----------------
__global__ __launch_bounds__(256) void k_fold(P p) {
  int tid = blockIdx.x*256 + threadIdx.x;
  char* ws = p.ws;
  if (tid < 196608) {
    int m_id = tid >> 16, o = (tid >> 9) & 127, c = tid & 511;
    const float* A  = m_id==0 ? p.in[9] : (m_id==1 ? p.in[7] : p.in[11]);   // w_q / w_k / w_v
    const float* Bm = (m_id==0) ? p.in[3] : p.in[5];                        // w_sq / w_so
    float acc = 0.f;
    #pragma unroll 8
    for (int m=0;m<128;m++) acc += A[o*128+m] * Bm[m*512+c];
    bf16* outw = (bf16*)(ws + (m_id==0?OFF_WQS: m_id==1?OFF_WKO:OFF_WVO));
    outw[o*512+c] = (bf16)acc;
  } else if (tid < 196992) {
    int t = tid - 196608; int m_id = t >> 7, o = t & 127;
    const float* A  = m_id==0 ? p.in[9] : (m_id==1 ? p.in[7] : p.in[11]);
    const float* bb = (m_id==0) ? p.in[4] : p.in[6];
    const float* bs = m_id==0 ? p.in[10] : (m_id==1 ? p.in[8] : p.in[12]);
    float acc = bs[o];
    for (int m=0;m<128;m++) acc += A[o*128+m] * bb[m];
    float* ob = (float*)(ws + (m_id==0?OFF_BQS: m_id==1?OFF_BKO:OFF_BVO));
    ob[o] = acc;
  } else if (tid < 197056) {
    int i = tid - 196992;
    float s = p.in[15][i] * rsqrtf(p.in[18][i] + 1e-5f);
    ((float*)(ws+OFF_S1))[i] = s;
    ((float*)(ws+OFF_T1))[i] = (p.in[14][i] - p.in[17][i])*s + p.in[16][i];
  } else if (tid < 197568) {
    int i = tid - 197056;
    float s = p.in[23][i] * rsqrtf(p.in[26][i] + 1e-5f);
    ((float*)(ws+OFF_S2))[i] = s;
    ((float*)(ws+OFF_T2))[i] = (p.in[22][i] - p.in[25][i])*s + p.in[24][i];  // b_a1 folded
  } else if (tid < 223168) {
    int e0 = (tid - 197568) * 8;
    const float* src; int base;
    if (e0 < 8192)        { src = p.in[19]; base = 0; }        // w_p2
    else if (e0 < 73728)  { src = p.in[21]; base = 8192; }     // w_a1
    else if (e0 < 139264) { src = p.in[29]; base = 73728; }    // w_a2
    else                  { src = p.in[27]; base = 139264; }   // w_e
    const float* sp = src + (e0 - base);
    f32x4 a = *(const f32x4*)sp, b2 = *(const f32x4*)(sp+4);
    bf16x8 o8;
    o8[0]=(bf16)a[0]; o8[1]=(bf16)a[1]; o8[2]=(bf16)a[2]; o8[3]=(bf16)a[3];
    o8[4]=(bf16)b2[0]; o8[5]=(bf16)b2[1]; o8[6]=(bf16)b2[2]; o8[7]=(bf16)b2[3];
    *(bf16x8*)((bf16*)(ws+OFF_CW) + e0) = o8;
  }
}

// ---------------- merged knn + qkv (independent work, co-scheduled for pipe overlap) ----------------
__global__ __launch_bounds__(256) void k_knnqkv(P p) {
  if (blockIdx.x < 768) {
    // ---- qkv: [128,512]x[512,4096] GEMM -> [n][c] transposed outputs ----
    int qb = blockIdx.x;
    int mat = qb >> 8, b = (qb >> 6) & 3, n0 = (qb & 63) * 64;
    int tid = threadIdx.x, lane = tid&63, w = tid>>6;
    const float* in = (mat==0 ? p.in[2] : p.in[0]) + b*CIN*NPTS;
    const bf16* W = (const bf16*)(p.ws + (mat==0?OFF_WQS: mat==1?OFF_WKO:OFF_WVO));
    const float* bias = (const float*)(p.ws + (mat==0?OFF_BQS: mat==1?OFF_BKO:OFF_BVO));
    bf16* outT = (bf16*)(p.ws + (mat==0?OFF_QT: mat==1?OFF_KT:OFF_VT)) + (b*NPTS + n0)*DIM;
    __shared__ __align__(16) bf16 Bl[64*40];   // [64 n][32 c + 8 pad]
    f32x4 acc[8] = {};
    for (int ks=0; ks<16; ks++) {
      int c0 = ks*32;
      {
        int cc = tid>>3, nn0 = (tid&7)*8;
        const float* sp = in + (c0+cc)*NPTS + n0 + nn0;
        f32x4 a = *(const f32x4*)sp, b2 = *(const f32x4*)(sp+4);
        Bl[(nn0+0)*40+cc]=(bf16)a[0];  Bl[(nn0+1)*40+cc]=(bf16)a[1];
        Bl[(nn0+2)*40+cc]=(bf16)a[2];  Bl[(nn0+3)*40+cc]=(bf16)a[3];
        Bl[(nn0+4)*40+cc]=(bf16)b2[0]; Bl[(nn0+5)*40+cc]=(bf16)b2[1];
        Bl[(nn0+6)*40+cc]=(bf16)b2[2]; Bl[(nn0+7)*40+cc]=(bf16)b2[3];
      }
      softbar();
      int ncol = w*16 + (lane&15);
      bf16x8 bfr = *(const bf16x8*)(&Bl[ncol*40 + (lane>>4)*8]);
      #pragma unroll
      for (int ot=0;ot<8;ot++) {
        bf16x8 af = *(const bf16x8*)(W + (ot*16 + (lane&15))*CIN + c0 + (lane>>4)*8);
        acc[ot] = MFMA16(af, bfr, acc[ot]);
      }
      softbar();
    }
    int o0 = (lane>>4)*4;
    int nloc = w*16 + (lane&15);
    #pragma unroll
    for (int ot=0;ot<8;ot++) {
      f32x4 bs = *(const f32x4*)(bias + ot*16 + o0);
      bf16x4 st;
      st[0]=(bf16)(acc[ot][0]+bs[0]); st[1]=(bf16)(acc[ot][1]+bs[1]);
      st[2]=(bf16)(acc[ot][2]+bs[2]); st[3]=(bf16)(acc[ot][3]+bs[3]);
      *(bf16x4*)(outT + nloc*DIM + ot*16 + o0) = st;
    }
    return;
  }
  // ---- knn: cached chain minima; only the affected chain rescanned per round ----
  int lane = threadIdx.x & 63, w = threadIdx.x >> 6;
  int ig = (blockIdx.x - 768)*4 + w;       // b*4096 + n, covers 4*4096 points
  int b = ig >> 12, n = ig & 4095;
  const float* pb = p.in[1] + b*3*NPTS;
  float qx = pb[n], qy = pb[NPTS+n], qz = pb[2*NPTS+n];
  float sqn = __fadd_rn(__fadd_rn(__fmul_rn(qx,qx), __fmul_rn(qy,qy)), __fmul_rn(qz,qz));
  unsigned u[64];
  #pragma unroll
  for (int t=0;t<64;t++) {
    int j = t*64 + lane;
    float xj=pb[j], yj=pb[NPTS+j], zj=pb[2*NPTS+j];
    float sqj = __fadd_rn(__fadd_rn(__fmul_rn(xj,xj), __fmul_rn(yj,yj)), __fmul_rn(zj,zj));
    float dot = __fadd_rn(__fadd_rn(__fmul_rn(qx,xj), __fmul_rn(qy,yj)), __fmul_rn(qz,zj));
    float d2 = __fadd_rn(__fsub_rn(sqn, __fmul_rn(2.f,dot)), sqj);
    unsigned bb2 = __float_as_uint(d2);
    u[t] = bb2 ^ (((unsigned)((int)bb2 >> 31)) | 0x80000000u);   // order-preserving f32->u32
  }
  unsigned v0=u[0], v1=u[16], v2=u[32], v3=u[48];
  int t0=0, t1=16, t2=32, t3=48;
  #pragma unroll
  for (int i=1;i<16;i++) {
    { bool lt=u[i]    <v0; v0=lt?u[i]   :v0; t0=lt?(i)   :t0; }
    { bool lt=u[16+i] <v1; v1=lt?u[16+i]:v1; t1=lt?(16+i):t1; }
    { bool lt=u[32+i] <v2; v2=lt?u[32+i]:v2; t2=lt?(32+i):t2; }
    { bool lt=u[48+i] <v3; v3=lt?u[48+i]:v3; t3=lt?(48+i):t3; }
  }
  int* op = (int*)(p.ws + OFF_IDX) + ig*16;
  #pragma unroll 1
  for (int r=0;r<16;r++) {
    unsigned va=v0; int ta=t0;
    { bool lt=v1<va; va=lt?v1:va; ta=lt?t1:ta; }
    unsigned vb=v2; int tb=t2;
    { bool lt=v3<vb; vb=lt?v3:vb; tb=lt?t3:tb; }
    { bool lt=vb<va; va=lt?vb:va; ta=lt?tb:ta; }
    unsigned long long key = ((unsigned long long)va << 12) | (unsigned)((ta<<6) | lane);
    { unsigned long long o = ror64<1>(key); if (o<key) key=o; }
    { unsigned long long o = ror64<2>(key); if (o<key) key=o; }
    { unsigned long long o = ror64<4>(key); if (o<key) key=o; }
    { unsigned long long o = ror64<8>(key); if (o<key) key=o; }
    { unsigned long long o = __shfl_xor(key,16); if (o<key) key=o; }
    { unsigned long long o = __shfl_xor(key,32); if (o<key) key=o; }
    unsigned jwin = (unsigned)key & 4095u;
    if (lane==0) op[r] = (int)jwin;
    if (r==15) break;
    int tsel = __builtin_amdgcn_readfirstlane((int)(jwin>>6));
    bool mine = ((int)(jwin&63)==lane);
    switch (tsel) {
#define CLR(T) case T: u[T] = mine ? 0xFFFFFFFFu : u[T]; break;
      CLR(0) CLR(1) CLR(2) CLR(3) CLR(4) CLR(5) CLR(6) CLR(7)
      CLR(8) CLR(9) CLR(10) CLR(11) CLR(12) CLR(13) CLR(14) CLR(15)
      CLR(16) CLR(17) CLR(18) CLR(19) CLR(20) CLR(21) CLR(22) CLR(23)
      CLR(24) CLR(25) CLR(26) CLR(27) CLR(28) CLR(29) CLR(30) CLR(31)
      CLR(32) CLR(33) CLR(34) CLR(35) CLR(36) CLR(37) CLR(38) CLR(39)
      CLR(40) CLR(41) CLR(42) CLR(43) CLR(44) CLR(45) CLR(46) CLR(47)
      CLR(48) CLR(49) CLR(50) CLR(51) CLR(52) CLR(53) CLR(54) CLR(55)
      CLR(56) CLR(57) CLR(58) CLR(59) CLR(60) CLR(61) CLR(62) CLR(63)
#undef CLR
      default: break;
    }
    switch (tsel >> 4) {
      case 0: { v0=u[0]; t0=0;
        #pragma unroll
        for (int i=1;i<16;i++){ bool lt=u[i]<v0; v0=lt?u[i]:v0; t0=lt?i:t0; } } break;
      case 1: { v1=u[16]; t1=16;
        #pragma unroll
        for (int i=1;i<16;i++){ bool lt=u[16+i]<v1; v1=lt?u[16+i]:v1; t1=lt?(16+i):t1; } } break;
      case 2: { v2=u[32]; t2=32;
        #pragma unroll
        for (int i=1;i<16;i++){ bool lt=u[32+i]<v2; v2=lt?u[32+i]:v2; t2=lt?(32+i):t2; } } break;
      default: { v3=u[48]; t3=48;
        #pragma unroll
        for (int i=1;i<16;i++){ bool lt=u[48+i]<v3; v3=lt?u[48+i]:v3; t3=lt?(48+i):t3; } } break;
    }
  }
}

// ---------------- fused: per block = 1 batch x 8 points; LDS 53.2K; drain-free barriers ----------------
__global__ __launch_bounds__(512) void k_fused(P p) {
  int bb = p.ybase + blockIdx.y, pt0 = blockIdx.x*8;
  int tid=threadIdx.x, lane=tid&63, w=tid>>6;
  int c = lane&15, g = lane>>4;
  char* ws = p.ws;
  const bf16* qT = (const bf16*)(ws+OFF_QT) + bb*NPTS*DIM;
  const bf16* kT = (const bf16*)(ws+OFF_KT) + bb*NPTS*DIM;
  const bf16* vT = (const bf16*)(ws+OFF_VT) + bb*NPTS*DIM;
  const int* idxg = (const int*)(ws+OFF_IDX) + (bb*NPTS + pt0)*16;
  const bf16* wp2b = (const bf16*)(ws+OFF_CW);
  const bf16* wa1b = wp2b + 8192;
  const bf16* wa2b = wa1b + 65536;
  const bf16* web  = wa2b + 65536;
  const float* s2 = (const float*)(ws+OFF_S2);
  const float* t2 = (const float*)(ws+OFF_T2);
  __shared__ __align__(16) char LB[53248];
  bf16* Xl = (bf16*)LB;            // [128 col][136]
  bf16* HT = (bf16*)(LB + 34816);  // [128 col][72]
  bf16* aggl = (bf16*)(LB + 34816);// [<=16 pt][136] overlays dead HT

  // phase 1: T1 = relu(bn1(w_p1 @ pos_rel)) -> HT[col][m]
  {
    int col = w*16 + c;
    int j = idxg[col] & 4095;
    const float* pb = p.in[1] + bb*3*NPTS;
    int n = pt0 + w;
    float r0 = pb[n]-pb[j], r1 = pb[NPTS+n]-pb[NPTS+j], r2 = pb[2*NPTS+n]-pb[2*NPTS+j];
    const float* wp1 = p.in[13];
    const float* s1 = (const float*)(ws+OFF_S1);
    const float* t1 = (const float*)(ws+OFF_T1);
    #pragma unroll
    for (int i=0;i<16;i+=2) {
      int m = g*16 + i;
      float x0 = wp1[m*3]*r0   + wp1[m*3+1]*r1 + wp1[m*3+2]*r2;
      float x1 = wp1[m*3+3]*r0 + wp1[m*3+4]*r1 + wp1[m*3+5]*r2;
      bf16x2 pk;
      pk[0] = (bf16)fmaxf(0.f, x0*s1[m]   + t1[m]);
      pk[1] = (bf16)fmaxf(0.f, x1*s1[m+1] + t1[m+1]);
      *(bf16x2*)(&HT[col*72 + m]) = pk;
    }
  }
  softbar();

  // phase 2: PE = w_p2 @ T1 + b_p2 ; X = q - k_g + PE -> Xl[col][c]
  {
    f32x4 acc[8] = {};
    int crow = w*16 + c;
    #pragma unroll
    for (int ksx=0; ksx<2; ksx++) {
      int m0 = ksx*32 + g*8;
      bf16x8 af = *(const bf16x8*)(wp2b + crow*PH + m0);
      #pragma unroll
      for (int nt=0; nt<8; nt++) {
        int col = nt*16 + c;
        bf16x8 bfr = *(const bf16x8*)(&HT[col*72 + m0]);
        acc[nt] = MFMA16(af, bfr, acc[nt]);
      }
    }
    int c0 = w*16 + g*4;
    f32x4 bp4 = *(const f32x4*)(p.in[20] + c0);
    #pragma unroll
    for (int nt=0; nt<8; nt++) {
      int col = nt*16 + c;
      int j = idxg[col] & 4095;
      int n = pt0 + nt;
      bf16x4 q4 = *(const bf16x4*)(qT + n*DIM + c0);
      bf16x4 k4 = *(const bf16x4*)(kT + j*DIM + c0);
      bf16x4 st;
      #pragma unroll
      for (int r=0;r<4;r++)
        st[r] = (bf16)((float)q4[r] - (float)k4[r] + acc[nt][r] + bp4[r]);
      *(bf16x4*)(&Xl[col*136 + c0]) = st;
    }
  }
  softbar();

  // phase 3: fused MLP, 8 chunks of 64 hidden rows
  f32x4 S[8] = {};
  for (int ch=0; ch<8; ch++) {
    f32x4 acc1[4] = {};
    int mtw = w & 3, nbase = (w>>2)*4;
    int hrow = ch*64 + mtw*16 + c;
    #pragma unroll
    for (int ksx=0; ksx<4; ksx++) {
      bf16x8 af = *(const bf16x8*)(wa1b + hrow*DIM + ksx*32 + g*8);
      #pragma unroll
      for (int i=0; i<4; i++) {
        int col = (nbase+i)*16 + c;
        bf16x8 bfr = *(const bf16x8*)(&Xl[col*136 + ksx*32 + g*8]);
        acc1[i] = MFMA16(af, bfr, acc1[i]);
      }
    }
    int h0 = ch*64 + mtw*16 + g*4;
    int h0loc = mtw*16 + g*4;
    f32x4 sv = *(const f32x4*)(s2 + h0);
    f32x4 tv = *(const f32x4*)(t2 + h0);
    #pragma unroll
    for (int i=0;i<4;i++) {
      int col = (nbase+i)*16 + c;
      bf16x4 st;
      st[0]=(bf16)fmaxf(0.f, acc1[i][0]*sv[0]+tv[0]);
      st[1]=(bf16)fmaxf(0.f, acc1[i][1]*sv[1]+tv[1]);
      st[2]=(bf16)fmaxf(0.f, acc1[i][2]*sv[2]+tv[2]);
      st[3]=(bf16)fmaxf(0.f, acc1[i][3]*sv[3]+tv[3]);
      *(bf16x4*)(&HT[col*72 + h0loc]) = st;
    }
    softbar();
    int orow = w*16 + c;
    #pragma unroll
    for (int ksx=0; ksx<2; ksx++) {
      bf16x8 af = *(const bf16x8*)(wa2b + orow*HID + ch*64 + ksx*32 + g*8);
      #pragma unroll
      for (int nt=0; nt<8; nt++) {
        int col = nt*16 + c;
        bf16x8 bfr = *(const bf16x8*)(&HT[col*72 + ksx*32 + g*8]);
        S[nt] = MFMA16(af, bfr, S[nt]);
      }
    }
    softbar();
  }

  // phase 4: softmax over k (16 lanes, DPP) + agg -> aggl (overlays dead HT)
  {
    int c0 = w*16 + g*4;
    #pragma unroll
    for (int nt=0; nt<8; nt++) {
      f32x4 s = S[nt];
      int col = nt*16 + c;
      int j = idxg[col] & 4095;
      int n = pt0 + nt;
      bf16x4 x4 = *(const bf16x4*)(&Xl[col*136 + c0]);
      bf16x4 q4 = *(const bf16x4*)(qT + n*DIM + c0);
      bf16x4 k4 = *(const bf16x4*)(kT + j*DIM + c0);
      bf16x4 v4 = *(const bf16x4*)(vT + n*DIM + c0);
      float agv[4];
      #pragma unroll
      for (int r=0;r<4;r++) {
        float mx = red16max(s[r]);
        float e = __expf(s[r]-mx);
        float sm = red16sum(e);
        float at = e/sm;
        float vpe = (float)v4[r] + (float)x4[r] - (float)q4[r] + (float)k4[r];
        agv[r] = red16sum(at*vpe);
      }
      if (c==0) {
        bf16x4 st; st[0]=(bf16)agv[0]; st[1]=(bf16)agv[1]; st[2]=(bf16)agv[2]; st[3]=(bf16)agv[3];
        *(bf16x4*)(&aggl[nt*136 + c0]) = st;
      }
    }
  }
  softbar();

  // phase 5: out = w_e @ agg + b_e
  {
    const float* be = p.in[28];
    f32x4 acc5[4] = {};
    #pragma unroll
    for (int ksx=0; ksx<4; ksx++) {
      bf16x8 bfr = *(const bf16x8*)(&aggl[c*136 + ksx*32 + g*8]);
      #pragma unroll
      for (int i=0;i<4;i++) {
        int e = (w*4+i)*16 + c;
        bf16x8 af = *(const bf16x8*)(web + e*DIM + ksx*32 + g*8);
        acc5[i] = MFMA16(af, bfr, acc5[i]);
      }
    }
    if (c < 8) {
      int n = pt0 + c;
      #pragma unroll
      for (int i=0;i<4;i++) {
        int e0 = (w*4+i)*16 + g*4;
        f32x4 be4 = *(const f32x4*)(be + e0);
        #pragma unroll
        for (int r=0;r<4;r++)
          p.out[(bb*CIN + e0+r)*NPTS + n] = acc5[i][r] + be4[r];
      }
    }
  }
}

extern "C" void kernel_launch(void* const* d_in, const int* in_sizes, int n_in,
                              void* d_out, int out_size, void* d_ws, size_t ws_size,
                              hipStream_t stream) {
  if (ws_size < WS_NEED || n_in < 31) return;  // loud failure: output stays zero
  P p;
  for (int i=0;i<31;i++) p.in[i] = (const float*)d_in[i];
  p.ws = (char*)d_ws;
  p.out = (float*)d_out;
  p.ybase = 0;
  k_fold<<<872, 256, 0, stream>>>(p);
  k_knnqkv<<<768 + 4096, 256, 0, stream>>>(p);   // 768 qkv blocks + 4096 knn blocks
  k_fused<<<dim3(512, 4), 512, 0, stream>>>(p);
}